// Round 1
// baseline (558.797 us; speedup 1.0000x reference)
//
#include <hip/hip_runtime.h>
#include <hip/hip_bf16.h>

typedef _Float16 f16;
typedef _Float16 half8 __attribute__((ext_vector_type(8)));
typedef float f32x4 __attribute__((ext_vector_type(4)));

// ---------------- workspace layout (bytes) ----------------
#define WQV_OFF   0u          // f32 [256][256]  Wq*Vp
#define WKT_OFF   262144u     // f32 [256][256]  Wk*Tp
#define KP_OFF    524288u     // f32 [512][256]  fused k-projection (l*16+b rows)
#define W2S_OFF   1048576u    // f16 [16][256][256] per-batch score matrix
#define SBIAS_OFF 3145728u    // f32 [16][256]
#define BQV_OFF   3162112u    // f32 [256]
#define BKT_OFF   3163136u    // f32 [256]
#define W1H_OFF   3164160u    // f16 [256][256]
#define W2H_OFF   3295232u    // f16 [128][256]
#define VARP_OFF  3360768u    // f32 [16][256]
#define KTOP_OFF  3377152u    // i32 [16]
#define SMM_OFF   3377280u    // u32 [16][2]  sim min/max (ordered-u32 mapped)
#define FMM_OFF   3377408u    // u32 [16][2]  fi  min/max
#define CAND_OFF  3377664u    // f32 [16][16384][9]  sim candidates for k=8..16
#define FI_OFF    12814848u   // f32 [16][16384]
#define SIM_OFF   13863424u   // f32 [16][16384]
// total: 14912000 bytes

__device__ __forceinline__ float sigm(float x) { return 1.f / (1.f + __expf(-x)); }
__device__ __forceinline__ unsigned fmap(float f) {
  unsigned u = __float_as_uint(f);
  return (u & 0x80000000u) ? ~u : (u | 0x80000000u);
}
__device__ __forceinline__ float funmap(unsigned u) {
  unsigned b = (u & 0x80000000u) ? (u & 0x7FFFFFFFu) : ~u;
  return __uint_as_float(b);
}

// ---------------- init min/max sentinels ----------------
__global__ void k_init(unsigned* __restrict__ simMM, unsigned* __restrict__ fiMM) {
  int t = threadIdx.x;
  if (t < 16) {
    simMM[t * 2] = 0xFFFFFFFFu; simMM[t * 2 + 1] = 0u;
    fiMM[t * 2] = 0xFFFFFFFFu;  fiMM[t * 2 + 1] = 0u;
  }
}

// ---------------- P1: Wqv = Wq*Vp, Wkt = Wk*Tp, fused biases ----------------
__global__ void k_p1(const float* __restrict__ ipw, const float* __restrict__ ipb,
                     const float* __restrict__ vp_w, const float* __restrict__ vp_b,
                     const float* __restrict__ tp_w, const float* __restrict__ tp_b,
                     float* __restrict__ Wqv, float* __restrict__ Wkt,
                     float* __restrict__ bqv, float* __restrict__ bkt) {
  int tx = threadIdx.x, ty = threadIdx.y;
  int bz = blockIdx.z;
  if (bz == 2) {
    if (blockIdx.x || blockIdx.y) return;
    int j = ty * 16 + tx;
    float s1 = 0.f, s2 = 0.f;
    for (int k = 0; k < 256; ++k) {
      s1 += ipw[j * 256 + k] * vp_b[k];
      s2 += ipw[65536 + j * 256 + k] * tp_b[k];
    }
    bqv[j] = s1 + ipb[j];
    bkt[j] = s2 + ipb[256 + j];
    return;
  }
  const float* A = ipw + (bz ? 65536 : 0);
  const float* B = bz ? tp_w : vp_w;
  float* O = bz ? Wkt : Wqv;
  __shared__ float As[16][16], Bs[16][17];
  int row = blockIdx.y * 16 + ty, col = blockIdx.x * 16 + tx;
  float s = 0.f;
  for (int tt = 0; tt < 16; ++tt) {
    As[ty][tx] = A[row * 256 + tt * 16 + tx];
    Bs[ty][tx] = B[(tt * 16 + ty) * 256 + col];
    __syncthreads();
#pragma unroll
    for (int k = 0; k < 16; ++k) s += As[ty][k] * Bs[k][tx];
    __syncthreads();
  }
  O[row * 256 + col] = s;
}

// ---------------- convert W1/W2 to f16 ----------------
__global__ void k_conv(const float* __restrict__ w1, const float* __restrict__ w2,
                       f16* __restrict__ W1h, f16* __restrict__ W2h) {
  int i = blockIdx.x * 256 + threadIdx.x;
  if (i < 65536) W1h[i] = (f16)w1[i];
  else if (i < 98304) W2h[i - 65536] = (f16)w2[i - 65536];
}

// ---------------- P2: kp[lb][i] = T[lb]·Wkt[i] + bkt[i] ----------------
__global__ void k_p2(const float* __restrict__ T, const float* __restrict__ Wkt,
                     const float* __restrict__ bkt, float* __restrict__ kp) {
  __shared__ float As[16][16], Ws[16][17];
  int tx = threadIdx.x, ty = threadIdx.y;
  int lb = blockIdx.y * 16 + ty;
  int i = blockIdx.x * 16 + tx;
  float s = 0.f;
  for (int tt = 0; tt < 16; ++tt) {
    As[ty][tx] = T[(size_t)lb * 256 + tt * 16 + tx];
    Ws[ty][tx] = Wkt[(size_t)(blockIdx.x * 16 + ty) * 256 + tt * 16 + tx];
    __syncthreads();
#pragma unroll
    for (int k = 0; k < 16; ++k) s += As[ty][k] * Ws[tx][k];
    __syncthreads();
  }
  kp[(size_t)lb * 256 + i] = s + bkt[i];
}

// ---------------- P3: W2s[b][h*32+l][c], sbias ----------------
__global__ void k_p3(const float* __restrict__ kp, const float* __restrict__ Wqv,
                     const float* __restrict__ bqv, f16* __restrict__ W2s,
                     float* __restrict__ sbias) {
  const float SC = 0.17677669529663687f; // 1/sqrt(32)
  int b = blockIdx.z, jt = blockIdx.y, ct = blockIdx.x;
  int ty = threadIdx.y, tx = threadIdx.x;
  int j2 = jt * 16 + ty, c = ct * 16 + tx;
  int h = j2 >> 5, l = j2 & 31;
  const float* kr = kp + (size_t)(l * 16 + b) * 256 + h * 32;
  const float* wq = Wqv + (size_t)h * 32 * 256 + c;
  float s = 0.f;
#pragma unroll
  for (int d = 0; d < 32; ++d) s += kr[d] * wq[(size_t)d * 256];
  W2s[(size_t)b * 65536 + j2 * 256 + c] = (f16)(s * SC);
  if (ct == 0 && tx == 0) {
    float sb = 0.f;
#pragma unroll
    for (int d = 0; d < 32; ++d) sb += kr[d] * bqv[h * 32 + d];
    sbias[b * 256 + j2] = sb * SC;
  }
}

// ---------------- G1: scores GEMM + softmax/head-mean + variance + top16 cands ----------------
__global__ void __launch_bounds__(256) k_g1(
    const float* __restrict__ X, const f16* __restrict__ W2s,
    const float* __restrict__ sbias, float* __restrict__ cand,
    float* __restrict__ varpart) {
  __shared__ char smem[65536]; // stage: A f16[64][64]@0 (8K), B f16[256][64]@8192 (32K); scores f32[64][256]@0 alias (64K)
  const int b = blockIdx.y;
  const int n0 = blockIdx.x * 64;
  const int t = threadIdx.x;
  const int w = t >> 6;
  const int lane = t & 63;
  const int ln = lane & 15, kg = lane >> 4;
  const int wrow = (w >> 1) * 32, wcol = (w & 1) * 128;

  f32x4 acc[2][8];
#pragma unroll
  for (int m = 0; m < 2; ++m)
#pragma unroll
    for (int n = 0; n < 8; ++n)
#pragma unroll
      for (int i = 0; i < 4; ++i) acc[m][n][i] = 0.f;

  const int ar = t >> 2, aq = t & 3;
  const float* Ap = X + (((size_t)(n0 + ar)) * 16 + b) * 256 + aq * 16;
  const unsigned asw = (unsigned)((ar & 7) << 4);
  const unsigned ab0 = (unsigned)(ar * 128 + aq * 32);
  const int bj = t >> 3, bq = t & 7;
  const uint4* Bp = (const uint4*)(W2s + (size_t)b * 65536);

  f32x4 af[4];
  uint4 bu[8];
#pragma unroll
  for (int i = 0; i < 4; ++i) af[i] = ((const f32x4*)Ap)[i];
#pragma unroll
  for (int p = 0; p < 8; ++p) bu[p] = Bp[(size_t)(bj + p * 32) * 32 + bq];

#pragma unroll
  for (int kt = 0; kt < 4; ++kt) {
    __syncthreads();
    { // store staged tile (f32->f16 for A, raw f16 for B), XOR-swizzled
      half8 h0, h1;
#pragma unroll
      for (int i = 0; i < 4; ++i) {
        h0[i] = (f16)af[0][i]; h0[4 + i] = (f16)af[1][i];
        h1[i] = (f16)af[2][i]; h1[4 + i] = (f16)af[3][i];
      }
      *(half8*)(smem + (ab0 ^ asw)) = h0;
      *(half8*)(smem + ((ab0 + 16) ^ asw)) = h1;
#pragma unroll
      for (int p = 0; p < 8; ++p) {
        int j = bj + p * 32;
        *(uint4*)(smem + 8192 + ((unsigned)(j * 128 + bq * 16) ^ (unsigned)((j & 7) << 4))) = bu[p];
      }
    }
    __syncthreads();
    if (kt < 3) { // prefetch next tile during MFMA
#pragma unroll
      for (int i = 0; i < 4; ++i) af[i] = ((const f32x4*)(Ap + (kt + 1) * 64))[i];
#pragma unroll
      for (int p = 0; p < 8; ++p) bu[p] = Bp[(size_t)(bj + p * 32) * 32 + (kt + 1) * 8 + bq];
    }
#pragma unroll
    for (int ks = 0; ks < 2; ++ks) {
      half8 av[2], bv[8];
#pragma unroll
      for (int m = 0; m < 2; ++m) {
        int R = wrow + m * 16 + ln;
        av[m] = *(const half8*)(smem + ((unsigned)(R * 128 + ks * 64 + kg * 16) ^ (unsigned)((R & 7) << 4)));
      }
#pragma unroll
      for (int n = 0; n < 8; ++n) {
        int J = wcol + n * 16 + ln;
        bv[n] = *(const half8*)(smem + 8192 + ((unsigned)(J * 128 + ks * 64 + kg * 16) ^ (unsigned)((J & 7) << 4)));
      }
#pragma unroll
      for (int m = 0; m < 2; ++m)
#pragma unroll
        for (int n = 0; n < 8; ++n)
          acc[m][n] = __builtin_amdgcn_mfma_f32_16x16x32_f16(av[m], bv[n], acc[m][n], 0, 0, 0);
    }
  }
  __syncthreads();

  { // bias + write scores tile to LDS (swizzled f32 [64][256])
    const float* sb = sbias + b * 256;
#pragma unroll
    for (int n = 0; n < 8; ++n) {
      int J = wcol + n * 16 + ln;
      float bias = sb[J];
#pragma unroll
      for (int m = 0; m < 2; ++m)
#pragma unroll
        for (int r = 0; r < 4; ++r) {
          int R = wrow + m * 16 + kg * 4 + r;
          *(float*)(smem + ((unsigned)(R * 1024 + J * 4) ^ (unsigned)((R & 7) << 4))) = acc[m][n][r] + bias;
        }
    }
  }
  __syncthreads();

  if (t < 64) { // one thread per row: softmax/head, mean, variance, top16, candidates
    const int r = t;
    const unsigned rsw = (unsigned)((r & 7) << 4);
    float v[32];
#pragma unroll
    for (int l = 0; l < 32; ++l) v[l] = 0.f;
#pragma unroll
    for (int h = 0; h < 8; ++h) {
      float s[32];
#pragma unroll
      for (int i = 0; i < 8; ++i) {
        f32x4 f = *(const f32x4*)(smem + ((unsigned)(r * 1024 + h * 128 + i * 16) ^ rsw));
#pragma unroll
        for (int c = 0; c < 4; ++c) s[i * 4 + c] = f[c];
      }
      float mx = s[0];
#pragma unroll
      for (int l = 1; l < 32; ++l) mx = fmaxf(mx, s[l]);
      float sum = 0.f;
#pragma unroll
      for (int l = 0; l < 32; ++l) { s[l] = __expf(s[l] - mx); sum += s[l]; }
      float inv = 0.125f / sum;
#pragma unroll
      for (int l = 0; l < 32; ++l) v[l] += s[l] * inv;
    }
    float s2 = 0.f;
#pragma unroll
    for (int l = 0; l < 32; ++l) s2 += v[l] * v[l];
    float vr = (s2 - (1.f / 32.f)) * (1.f / 31.f); // unbiased var, mean=1/32 exact
#pragma unroll
    for (int msk = 1; msk < 64; msk <<= 1) vr += __shfl_xor(vr, msk, 64);
    if (t == 0) varpart[b * 256 + blockIdx.x] = vr;

    // bitonic sort descending (static indices -> registers)
#pragma unroll
    for (int k = 2; k <= 32; k <<= 1) {
#pragma unroll
      for (int j = k >> 1; j > 0; j >>= 1) {
#pragma unroll
        for (int i = 0; i < 32; ++i) {
          int l = i ^ j;
          if (l > i) {
            float a = v[i], c = v[l];
            float hi = fmaxf(a, c), lo = fminf(a, c);
            bool up = ((i & k) == 0);
            v[i] = up ? hi : lo;
            v[l] = up ? lo : hi;
          }
        }
      }
    }
    // similarity candidates for k = 8..16
    float m0 = v[0], se = 0.f, te = 0.f;
    float cn[9];
#pragma unroll
    for (int i = 0; i < 16; ++i) {
      float e = __expf(v[i] - m0);
      se += e; te += v[i] * e;
      if (i >= 7) cn[i - 7] = te / se;
    }
    float* cp = cand + ((size_t)b * 16384 + n0 + r) * 9;
#pragma unroll
    for (int i = 0; i < 9; ++i) cp[i] = cn[i];
  }
}

// ---------------- G2: fused MLP (GEMM+LN+ReLU, GEMM+LN+ReLU, dot+sigmoid) ----------------
__global__ void __launch_bounds__(256) k_g2(
    const float* __restrict__ X, const f16* __restrict__ W1h,
    const float* __restrict__ b1, const float* __restrict__ g1, const float* __restrict__ be1,
    const f16* __restrict__ W2h, const float* __restrict__ b2,
    const float* __restrict__ g2, const float* __restrict__ be2,
    const float* __restrict__ w3, const float* __restrict__ b3,
    float* __restrict__ fi) {
  // stage1: A f16[64][64]@0, B f16[256][64]@8192 ; stage2: W2 tile f16[128][64]@0, h1 f16[64][256]@16384
  __shared__ char smem[49152];
  __shared__ float pS[64][2], pQ[64][2];
  const int r0 = blockIdx.x * 64;
  const int t = threadIdx.x;
  const int w = t >> 6;
  const int lane = t & 63;
  const int ln = lane & 15, kg = lane >> 4;
  const int wrow = (w >> 1) * 32, wcol = (w & 1) * 128;

  f32x4 acc[2][8];
#pragma unroll
  for (int m = 0; m < 2; ++m)
#pragma unroll
    for (int n = 0; n < 8; ++n)
#pragma unroll
      for (int i = 0; i < 4; ++i) acc[m][n][i] = 0.f;

  const int ar = t >> 2, aq = t & 3;
  const float* Ap = X + (size_t)(r0 + ar) * 256 + aq * 16;
  const unsigned asw = (unsigned)((ar & 7) << 4);
  const unsigned ab0 = (unsigned)(ar * 128 + aq * 32);
  const int bj = t >> 3, bq = t & 7;
  const uint4* Bp = (const uint4*)W1h;

  f32x4 af[4];
  uint4 bu[8];
#pragma unroll
  for (int i = 0; i < 4; ++i) af[i] = ((const f32x4*)Ap)[i];
#pragma unroll
  for (int p = 0; p < 8; ++p) bu[p] = Bp[(size_t)(bj + p * 32) * 32 + bq];

#pragma unroll
  for (int kt = 0; kt < 4; ++kt) {
    __syncthreads();
    {
      half8 h0, h1;
#pragma unroll
      for (int i = 0; i < 4; ++i) {
        h0[i] = (f16)af[0][i]; h0[4 + i] = (f16)af[1][i];
        h1[i] = (f16)af[2][i]; h1[4 + i] = (f16)af[3][i];
      }
      *(half8*)(smem + (ab0 ^ asw)) = h0;
      *(half8*)(smem + ((ab0 + 16) ^ asw)) = h1;
#pragma unroll
      for (int p = 0; p < 8; ++p) {
        int j = bj + p * 32;
        *(uint4*)(smem + 8192 + ((unsigned)(j * 128 + bq * 16) ^ (unsigned)((j & 7) << 4))) = bu[p];
      }
    }
    __syncthreads();
    if (kt < 3) {
#pragma unroll
      for (int i = 0; i < 4; ++i) af[i] = ((const f32x4*)(Ap + (kt + 1) * 64))[i];
#pragma unroll
      for (int p = 0; p < 8; ++p) bu[p] = Bp[(size_t)(bj + p * 32) * 32 + (kt + 1) * 8 + bq];
    }
#pragma unroll
    for (int ks = 0; ks < 2; ++ks) {
      half8 av[2], bv[8];
#pragma unroll
      for (int m = 0; m < 2; ++m) {
        int R = wrow + m * 16 + ln;
        av[m] = *(const half8*)(smem + ((unsigned)(R * 128 + ks * 64 + kg * 16) ^ (unsigned)((R & 7) << 4)));
      }
#pragma unroll
      for (int n = 0; n < 8; ++n) {
        int J = wcol + n * 16 + ln;
        bv[n] = *(const half8*)(smem + 8192 + ((unsigned)(J * 128 + ks * 64 + kg * 16) ^ (unsigned)((J & 7) << 4)));
      }
#pragma unroll
      for (int m = 0; m < 2; ++m)
#pragma unroll
        for (int n = 0; n < 8; ++n)
          acc[m][n] = __builtin_amdgcn_mfma_f32_16x16x32_f16(av[m], bv[n], acc[m][n], 0, 0, 0);
    }
  }
  __syncthreads();

  // ---- b1 + LayerNorm1 + ReLU -> h1 (f16, swizzled) ----
  float b1v[8], g1v[8], e1v[8];
#pragma unroll
  for (int n = 0; n < 8; ++n) {
    int J = wcol + n * 16 + ln;
    b1v[n] = b1[J]; g1v[n] = g1[J]; e1v[n] = be1[J];
  }
#pragma unroll
  for (int n = 0; n < 8; ++n)
#pragma unroll
    for (int m = 0; m < 2; ++m)
#pragma unroll
      for (int r = 0; r < 4; ++r) acc[m][n][r] += b1v[n];
#pragma unroll
  for (int m = 0; m < 2; ++m)
#pragma unroll
    for (int r = 0; r < 4; ++r) {
      float s = 0.f, q = 0.f;
#pragma unroll
      for (int n = 0; n < 8; ++n) { float x = acc[m][n][r]; s += x; q += x * x; }
#pragma unroll
      for (int msk = 1; msk < 16; msk <<= 1) { s += __shfl_xor(s, msk, 64); q += __shfl_xor(q, msk, 64); }
      if (ln == 0) { int R = wrow + m * 16 + kg * 4 + r; pS[R][w & 1] = s; pQ[R][w & 1] = q; }
    }
  __syncthreads();
#pragma unroll
  for (int m = 0; m < 2; ++m)
#pragma unroll
    for (int r = 0; r < 4; ++r) {
      int R = wrow + m * 16 + kg * 4 + r;
      float mean = (pS[R][0] + pS[R][1]) * (1.f / 256.f);
      float var = (pQ[R][0] + pQ[R][1]) * (1.f / 256.f) - mean * mean;
      float rstd = rsqrtf(var + 1e-5f);
#pragma unroll
      for (int n = 0; n < 8; ++n) {
        int J = wcol + n * 16 + ln;
        float y = (acc[m][n][r] - mean) * rstd * g1v[n] + e1v[n];
        y = fmaxf(y, 0.f);
        *(f16*)(smem + 16384 + ((unsigned)(R * 512 + J * 2) ^ (unsigned)((R & 7) << 4))) = (f16)y;
      }
    }
  __syncthreads();

  // ---- stage 2: h2 = h1 @ W2^T ----
  f32x4 acc2[2][4];
#pragma unroll
  for (int m = 0; m < 2; ++m)
#pragma unroll
    for (int n = 0; n < 4; ++n)
#pragma unroll
      for (int i = 0; i < 4; ++i) acc2[m][n][i] = 0.f;
  const int wcol2 = (w & 1) * 64;
  const int w2j = t >> 1, w2q = t & 1;
  const uint4* W2p = (const uint4*)W2h;
  uint4 wu[4];
#pragma unroll
  for (int i = 0; i < 4; ++i) wu[i] = W2p[(size_t)w2j * 32 + w2q * 4 + i];
#pragma unroll
  for (int kt = 0; kt < 4; ++kt) {
    __syncthreads();
#pragma unroll
    for (int i = 0; i < 4; ++i)
      *(uint4*)(smem + ((unsigned)(w2j * 128 + (w2q * 32 + i * 8) * 2) ^ (unsigned)((w2j & 7) << 4))) = wu[i];
    __syncthreads();
    if (kt < 3) {
#pragma unroll
      for (int i = 0; i < 4; ++i) wu[i] = W2p[(size_t)w2j * 32 + (kt + 1) * 8 + w2q * 4 + i];
    }
#pragma unroll
    for (int ks = 0; ks < 2; ++ks) {
      half8 av[2], bv[4];
#pragma unroll
      for (int m = 0; m < 2; ++m) {
        int R = wrow + m * 16 + ln;
        av[m] = *(const half8*)(smem + 16384 + ((unsigned)(R * 512 + kt * 128 + ks * 64 + kg * 16) ^ (unsigned)((R & 7) << 4)));
      }
#pragma unroll
      for (int n = 0; n < 4; ++n) {
        int J = wcol2 + n * 16 + ln;
        bv[n] = *(const half8*)(smem + ((unsigned)(J * 128 + ks * 64 + kg * 16) ^ (unsigned)((J & 7) << 4)));
      }
#pragma unroll
      for (int m = 0; m < 2; ++m)
#pragma unroll
        for (int n = 0; n < 4; ++n)
          acc2[m][n] = __builtin_amdgcn_mfma_f32_16x16x32_f16(av[m], bv[n], acc2[m][n], 0, 0, 0);
    }
  }
  __syncthreads();

  // ---- b2 + LayerNorm2 + ReLU + w3 dot + sigmoid ----
  float b2v[4], g2v[4], e2v[4], w3v[4];
#pragma unroll
  for (int n = 0; n < 4; ++n) {
    int J = wcol2 + n * 16 + ln;
    b2v[n] = b2[J]; g2v[n] = g2[J]; e2v[n] = be2[J]; w3v[n] = w3[J];
  }
#pragma unroll
  for (int n = 0; n < 4; ++n)
#pragma unroll
    for (int m = 0; m < 2; ++m)
#pragma unroll
      for (int r = 0; r < 4; ++r) acc2[m][n][r] += b2v[n];
#pragma unroll
  for (int m = 0; m < 2; ++m)
#pragma unroll
    for (int r = 0; r < 4; ++r) {
      float s = 0.f, q = 0.f;
#pragma unroll
      for (int n = 0; n < 4; ++n) { float x = acc2[m][n][r]; s += x; q += x * x; }
#pragma unroll
      for (int msk = 1; msk < 16; msk <<= 1) { s += __shfl_xor(s, msk, 64); q += __shfl_xor(q, msk, 64); }
      if (ln == 0) { int R = wrow + m * 16 + kg * 4 + r; pS[R][w & 1] = s; pQ[R][w & 1] = q; }
    }
  __syncthreads();
  float fp[2][4];
#pragma unroll
  for (int m = 0; m < 2; ++m)
#pragma unroll
    for (int r = 0; r < 4; ++r) {
      int R = wrow + m * 16 + kg * 4 + r;
      float mean = (pS[R][0] + pS[R][1]) * (1.f / 128.f);
      float var = (pQ[R][0] + pQ[R][1]) * (1.f / 128.f) - mean * mean;
      float rstd = rsqrtf(var + 1e-5f);
      float a3 = 0.f;
#pragma unroll
      for (int n = 0; n < 4; ++n) {
        float y = (acc2[m][n][r] - mean) * rstd * g2v[n] + e2v[n];
        y = fmaxf(y, 0.f);
        a3 += y * w3v[n];
      }
#pragma unroll
      for (int msk = 1; msk < 16; msk <<= 1) a3 += __shfl_xor(a3, msk, 64);
      fp[m][r] = a3;
    }
  __syncthreads();
  if (ln == 0) {
#pragma unroll
    for (int m = 0; m < 2; ++m)
#pragma unroll
      for (int r = 0; r < 4; ++r) {
        int R = wrow + m * 16 + kg * 4 + r;
        pS[R][w & 1] = fp[m][r];
      }
  }
  __syncthreads();
  if (((w & 1) == 0) && (ln == 0)) {
    float b3v = b3[0];
#pragma unroll
    for (int m = 0; m < 2; ++m)
#pragma unroll
      for (int r = 0; r < 4; ++r) {
        int R = wrow + m * 16 + kg * 4 + r;
        int rg = r0 + R; // rg = n*16 + b
        float z = pS[R][0] + pS[R][1] + b3v;
        fi[(size_t)(rg & 15) * 16384 + (rg >> 4)] = sigm(z);
      }
  }
}

// ---------------- G3: k_top per batch ----------------
__global__ void k_g3(const float* __restrict__ varpart, const float* __restrict__ kw,
                     int* __restrict__ ktop) {
  int t = threadIdx.x;
  int b = t >> 4, i = t & 15;
  float s = 0.f;
#pragma unroll
  for (int k = 0; k < 16; ++k) s += varpart[b * 256 + i + k * 16];
#pragma unroll
  for (int msk = 1; msk < 16; msk <<= 1) s += __shfl_xor(s, msk, 64);
  if (i == 0) {
    float var = s * (1.f / 16384.f);
    float kws = sigm(kw[0]);
    float ratio = kws * (1.f + var * 0.5f);
    ratio = fminf(fmaxf(ratio, 0.25f), 0.6f);
    int kb = (int)floorf(32.f * ratio);
    if (kb < 1) kb = 1;
    int kt = kb < 16 ? kb : 16;
    if (kt < 8) kt = 8;
    ktop[b] = kt;
  }
}

// ---------------- G4: pick sim candidate, min/max reductions ----------------
__global__ void __launch_bounds__(256) k_g4(
    const float* __restrict__ cand, const float* __restrict__ fi,
    const int* __restrict__ ktop, float* __restrict__ sim,
    unsigned* __restrict__ simMM, unsigned* __restrict__ fiMM) {
  __shared__ float red[4][4];
  int b = blockIdx.x >> 6;
  int n = (blockIdx.x & 63) * 256 + threadIdx.x;
  size_t idx = (size_t)b * 16384 + n;
  int k = ktop[b];
  float sv = cand[idx * 9 + (k - 8)];
  sim[idx] = sv;
  float fv = fi[idx];
  float sn = sv, sx = sv, fn = fv, fx = fv;
#pragma unroll
  for (int msk = 1; msk < 64; msk <<= 1) {
    sn = fminf(sn, __shfl_xor(sn, msk, 64));
    sx = fmaxf(sx, __shfl_xor(sx, msk, 64));
    fn = fminf(fn, __shfl_xor(fn, msk, 64));
    fx = fmaxf(fx, __shfl_xor(fx, msk, 64));
  }
  int w = threadIdx.x >> 6;
  if ((threadIdx.x & 63) == 0) { red[0][w] = sn; red[1][w] = sx; red[2][w] = fn; red[3][w] = fx; }
  __syncthreads();
  if (threadIdx.x == 0) {
    float a = red[0][0], c = red[1][0], d = red[2][0], e = red[3][0];
#pragma unroll
    for (int i = 1; i < 4; ++i) {
      a = fminf(a, red[0][i]); c = fmaxf(c, red[1][i]);
      d = fminf(d, red[2][i]); e = fmaxf(e, red[3][i]);
    }
    atomicMin(&simMM[b * 2 + 0], fmap(a));
    atomicMax(&simMM[b * 2 + 1], fmap(c));
    atomicMin(&fiMM[b * 2 + 0], fmap(d));
    atomicMax(&fiMM[b * 2 + 1], fmap(e));
  }
}

// ---------------- G5: normalize, combine, transpose-write ----------------
__global__ void __launch_bounds__(256) k_g5(
    const float* __restrict__ sim, const float* __restrict__ fi,
    const unsigned* __restrict__ simMM, const unsigned* __restrict__ fiMM,
    const float* __restrict__ ac, const float* __restrict__ af,
    float* __restrict__ out) {
  __shared__ float ls[256][17], lf[256][17];
  __shared__ float sMin[16], sInv[16], fMin[16], fInv[16];
  int t = threadIdx.x;
  int n0 = blockIdx.x * 256;
  if (t < 16) {
    float lo = funmap(simMM[t * 2]), hi = funmap(simMM[t * 2 + 1]);
    float r = hi - lo;
    sMin[t] = lo; sInv[t] = (r > 0.f) ? 1.f / r : 0.f;
    lo = funmap(fiMM[t * 2]); hi = funmap(fiMM[t * 2 + 1]);
    r = hi - lo;
    fMin[t] = lo; fInv[t] = (r > 0.f) ? 1.f / r : 0.f;
  }
#pragma unroll
  for (int i = 0; i < 16; ++i) {
    ls[t][i] = sim[(size_t)i * 16384 + n0 + t];
    lf[t][i] = fi[(size_t)i * 16384 + n0 + t];
  }
  __syncthreads();
  float alpha = 0.5f * (sigm(ac[0]) + sigm(af[0]));
  float o[16];
#pragma unroll
  for (int b = 0; b < 16; ++b) {
    float s = (ls[t][b] - sMin[b]) * sInv[b];
    float f = (lf[t][b] - fMin[b]) * fInv[b];
    o[b] = alpha * s + (1.f - alpha) * f;
  }
  float* op = out + (size_t)(n0 + t) * 16;
#pragma unroll
  for (int i = 0; i < 4; ++i) {
    f32x4 v;
    v[0] = o[i * 4]; v[1] = o[i * 4 + 1]; v[2] = o[i * 4 + 2]; v[3] = o[i * 4 + 3];
    *(f32x4*)(op + i * 4) = v;
  }
}

// ---------------- launcher ----------------
extern "C" void kernel_launch(void* const* d_in, const int* in_sizes, int n_in,
                              void* d_out, int out_size, void* d_ws, size_t ws_size,
                              hipStream_t stream) {
  const float* X    = (const float*)d_in[0];
  const float* T    = (const float*)d_in[1];
  const float* vp_w = (const float*)d_in[2];
  const float* vp_b = (const float*)d_in[3];
  const float* tp_w = (const float*)d_in[4];
  const float* tp_b = (const float*)d_in[5];
  const float* ipw  = (const float*)d_in[6];
  const float* ipb  = (const float*)d_in[7];
  const float* w1   = (const float*)d_in[8];
  const float* b1   = (const float*)d_in[9];
  const float* g1   = (const float*)d_in[10];
  const float* be1  = (const float*)d_in[11];
  const float* w2   = (const float*)d_in[12];
  const float* b2   = (const float*)d_in[13];
  const float* g2   = (const float*)d_in[14];
  const float* be2  = (const float*)d_in[15];
  const float* w3   = (const float*)d_in[16];
  const float* b3   = (const float*)d_in[17];
  const float* kw   = (const float*)d_in[18];
  const float* ac   = (const float*)d_in[19];
  const float* af   = (const float*)d_in[20];
  char* ws = (char*)d_ws;
  float* Wqv = (float*)(ws + WQV_OFF);
  float* Wkt = (float*)(ws + WKT_OFF);
  float* kp = (float*)(ws + KP_OFF);
  f16* W2s = (f16*)(ws + W2S_OFF);
  float* sbias = (float*)(ws + SBIAS_OFF);
  float* bqv = (float*)(ws + BQV_OFF);
  float* bkt = (float*)(ws + BKT_OFF);
  f16* W1h = (f16*)(ws + W1H_OFF);
  f16* W2h = (f16*)(ws + W2H_OFF);
  float* varpart = (float*)(ws + VARP_OFF);
  int* ktop = (int*)(ws + KTOP_OFF);
  unsigned* simMM = (unsigned*)(ws + SMM_OFF);
  unsigned* fiMM = (unsigned*)(ws + FMM_OFF);
  float* cand = (float*)(ws + CAND_OFF);
  float* fi = (float*)(ws + FI_OFF);
  float* sim = (float*)(ws + SIM_OFF);
  float* out = (float*)d_out;

  k_init<<<1, 32, 0, stream>>>(simMM, fiMM);
  k_p1<<<dim3(16, 16, 3), dim3(16, 16), 0, stream>>>(ipw, ipb, vp_w, vp_b, tp_w, tp_b, Wqv, Wkt, bqv, bkt);
  k_conv<<<384, 256, 0, stream>>>(w1, w2, W1h, W2h);
  k_p2<<<dim3(16, 32), dim3(16, 16), 0, stream>>>(T, Wkt, bkt, kp);
  k_p3<<<dim3(16, 16, 16), dim3(16, 16), 0, stream>>>(kp, Wqv, bqv, W2s, sbias);
  k_g1<<<dim3(256, 16), 256, 0, stream>>>(X, W2s, sbias, cand, varpart);
  k_g2<<<4096, 256, 0, stream>>>(X, W1h, b1, g1, be1, W2h, b2, g2, be2, w3, b3, fi);
  k_g3<<<1, 256, 0, stream>>>(varpart, kw, ktop);
  k_g4<<<1024, 256, 0, stream>>>(cand, fi, ktop, sim, simMM, fiMM);
  k_g5<<<64, 256, 0, stream>>>(sim, fi, simMM, fiMM, ac, af, out);
}

// Round 2
// 334.759 us; speedup vs baseline: 1.6693x; 1.6693x over previous
//
#include <hip/hip_runtime.h>
#include <hip/hip_bf16.h>

typedef _Float16 f16;
typedef _Float16 half8 __attribute__((ext_vector_type(8)));
typedef float f32x4 __attribute__((ext_vector_type(4)));

typedef const __attribute__((address_space(1))) void gvoid;
typedef __attribute__((address_space(3))) void lvoid;
// async global->LDS, 16B per lane, LDS dest = wave-uniform base + lane*16
#define GLOAD16(src, dst) __builtin_amdgcn_global_load_lds((gvoid*)(src), (lvoid*)(dst), 16, 0, 0)

// ---------------- workspace layout (bytes) ----------------
#define WQV_OFF   0u          // f32 [256][256]  Wq*Vp
#define WKT_OFF   262144u     // f32 [256][256]  Wk*Tp
#define KP_OFF    524288u     // f32 [512][256]  fused k-projection (l*16+b rows)
#define W2S_OFF   1048576u    // f16 [16][256][256] per-batch score matrix
#define SBIAS_OFF 3145728u    // f32 [16][256]
#define BQV_OFF   3162112u    // f32 [256]
#define BKT_OFF   3163136u    // f32 [256]
#define W1H_OFF   3164160u    // f16 [256][256]
#define W2H_OFF   3295232u    // f16 [128][256]
#define VARP_OFF  3360768u    // f32 [16][256]
#define KTOP_OFF  3377152u    // i32 [16]
#define SMM_OFF   3377280u    // u32 [16][2]  sim min/max (ordered-u32 mapped)
#define FMM_OFF   3377408u    // u32 [16][2]  fi  min/max
#define CAND_OFF  3377664u    // f32 [16][16384][9]  sim candidates for k=8..16
#define FI_OFF    12814848u   // f32 [16][16384]
#define SIM_OFF   13863424u   // f32 [16][16384]
// total: 14912000 bytes

__device__ __forceinline__ float sigm(float x) { return 1.f / (1.f + __expf(-x)); }
__device__ __forceinline__ unsigned fmap(float f) {
  unsigned u = __float_as_uint(f);
  return (u & 0x80000000u) ? ~u : (u | 0x80000000u);
}
__device__ __forceinline__ float funmap(unsigned u) {
  unsigned b = (u & 0x80000000u) ? (u & 0x7FFFFFFFu) : ~u;
  return __uint_as_float(b);
}

// ---------------- init min/max sentinels ----------------
__global__ void k_init(unsigned* __restrict__ simMM, unsigned* __restrict__ fiMM) {
  int t = threadIdx.x;
  if (t < 16) {
    simMM[t * 2] = 0xFFFFFFFFu; simMM[t * 2 + 1] = 0u;
    fiMM[t * 2] = 0xFFFFFFFFu;  fiMM[t * 2 + 1] = 0u;
  }
}

// ---------------- P1: Wqv = Wq*Vp, Wkt = Wk*Tp, fused biases ----------------
__global__ void k_p1(const float* __restrict__ ipw, const float* __restrict__ ipb,
                     const float* __restrict__ vp_w, const float* __restrict__ vp_b,
                     const float* __restrict__ tp_w, const float* __restrict__ tp_b,
                     float* __restrict__ Wqv, float* __restrict__ Wkt,
                     float* __restrict__ bqv, float* __restrict__ bkt) {
  int tx = threadIdx.x, ty = threadIdx.y;
  int bz = blockIdx.z;
  if (bz == 2) {
    if (blockIdx.x || blockIdx.y) return;
    int j = ty * 16 + tx;
    float s1 = 0.f, s2 = 0.f;
    for (int k = 0; k < 256; ++k) {
      s1 += ipw[j * 256 + k] * vp_b[k];
      s2 += ipw[65536 + j * 256 + k] * tp_b[k];
    }
    bqv[j] = s1 + ipb[j];
    bkt[j] = s2 + ipb[256 + j];
    return;
  }
  const float* A = ipw + (bz ? 65536 : 0);
  const float* B = bz ? tp_w : vp_w;
  float* O = bz ? Wkt : Wqv;
  __shared__ float As[16][16], Bs[16][17];
  int row = blockIdx.y * 16 + ty, col = blockIdx.x * 16 + tx;
  float s = 0.f;
  for (int tt = 0; tt < 16; ++tt) {
    As[ty][tx] = A[row * 256 + tt * 16 + tx];
    Bs[ty][tx] = B[(tt * 16 + ty) * 256 + col];
    __syncthreads();
#pragma unroll
    for (int k = 0; k < 16; ++k) s += As[ty][k] * Bs[k][tx];
    __syncthreads();
  }
  O[row * 256 + col] = s;
}

// ---------------- convert W1/W2 to f16 ----------------
__global__ void k_conv(const float* __restrict__ w1, const float* __restrict__ w2,
                       f16* __restrict__ W1h, f16* __restrict__ W2h) {
  int i = blockIdx.x * 256 + threadIdx.x;
  if (i < 65536) W1h[i] = (f16)w1[i];
  else if (i < 98304) W2h[i - 65536] = (f16)w2[i - 65536];
}

// ---------------- P2: kp[lb][i] = T[lb]·Wkt[i] + bkt[i] ----------------
__global__ void k_p2(const float* __restrict__ T, const float* __restrict__ Wkt,
                     const float* __restrict__ bkt, float* __restrict__ kp) {
  __shared__ float As[16][16], Ws[16][17];
  int tx = threadIdx.x, ty = threadIdx.y;
  int lb = blockIdx.y * 16 + ty;
  int i = blockIdx.x * 16 + tx;
  float s = 0.f;
  for (int tt = 0; tt < 16; ++tt) {
    As[ty][tx] = T[(size_t)lb * 256 + tt * 16 + tx];
    Ws[ty][tx] = Wkt[(size_t)(blockIdx.x * 16 + ty) * 256 + tt * 16 + tx];
    __syncthreads();
#pragma unroll
    for (int k = 0; k < 16; ++k) s += As[ty][k] * Ws[tx][k];
    __syncthreads();
  }
  kp[(size_t)lb * 256 + i] = s + bkt[i];
}

// ---------------- P3: W2s[b][h*32+l][c], sbias ----------------
__global__ void k_p3(const float* __restrict__ kp, const float* __restrict__ Wqv,
                     const float* __restrict__ bqv, f16* __restrict__ W2s,
                     float* __restrict__ sbias) {
  const float SC = 0.17677669529663687f; // 1/sqrt(32)
  int b = blockIdx.z, jt = blockIdx.y, ct = blockIdx.x;
  int ty = threadIdx.y, tx = threadIdx.x;
  int j2 = jt * 16 + ty, c = ct * 16 + tx;
  int h = j2 >> 5, l = j2 & 31;
  const float* kr = kp + (size_t)(l * 16 + b) * 256 + h * 32;
  const float* wq = Wqv + (size_t)h * 32 * 256 + c;
  float s = 0.f;
#pragma unroll
  for (int d = 0; d < 32; ++d) s += kr[d] * wq[(size_t)d * 256];
  W2s[(size_t)b * 65536 + j2 * 256 + c] = (f16)(s * SC);
  if (ct == 0 && tx == 0) {
    float sb = 0.f;
#pragma unroll
    for (int d = 0; d < 32; ++d) sb += kr[d] * bqv[h * 32 + d];
    sbias[b * 256 + j2] = sb * SC;
  }
}

// ---------------- G1: scores GEMM + in-register softmax/head-mean + variance + top16 ----------------
__global__ void __launch_bounds__(256, 2) k_g1(
    const float* __restrict__ X, const f16* __restrict__ W2s,
    const float* __restrict__ sbias, float* __restrict__ cand,
    float* __restrict__ varpart) {
  // A f16[64][64]@0 (8K), B f16[256][64]@8192 (32K), vpart f32[2][64][33]@40960 (16.9K)
  __shared__ __align__(16) char smem[58368];
  const int b = blockIdx.y;
  const int n0 = blockIdx.x * 64;
  const int t = threadIdx.x;
  const int w = t >> 6;
  const int lane = t & 63;
  const int ln = lane & 15, kg = lane >> 4;
  const int wrow = (w >> 1) * 32, wcol = (w & 1) * 128;

  f32x4 acc[2][8];
#pragma unroll
  for (int m = 0; m < 2; ++m)
#pragma unroll
    for (int n = 0; n < 8; ++n)
#pragma unroll
      for (int i = 0; i < 4; ++i) acc[m][n][i] = 0.f;

  const int ar = t >> 2, aq = t & 3;
  const float* Ap = X + (((size_t)(n0 + ar)) * 16 + b) * 256 + aq * 16;
  const unsigned asw = (unsigned)((ar & 7) << 4);
  const unsigned ab0 = (unsigned)(ar * 128 + aq * 32);

  // B staging via global_load_lds: linear LDS dest, pre-swizzled global source
  const char* Bg = (const char*)(W2s + (size_t)b * 65536);
  const int bj = lane >> 3;  // row within 8-row group
  const int bc = lane & 7;   // dest 16B chunk within row

  f32x4 af[4];
#pragma unroll
  for (int i = 0; i < 4; ++i) af[i] = ((const f32x4*)Ap)[i];

#pragma unroll
  for (int kt = 0; kt < 4; ++kt) {
    __syncthreads();
    // issue B tile loads (256 rows x 64 cols f16): 8 issues/wave, no VGPR staging
#pragma unroll
    for (int i = 0; i < 8; ++i) {
      int j0 = w * 64 + i * 8;
      int j = j0 + bj;
      GLOAD16(Bg + (size_t)j * 512 + kt * 128 + ((bc ^ (j & 7)) << 4),
              smem + 8192 + j0 * 128);
    }
    { // A store from prefetched regs (f32->f16, XOR-swizzled)
      half8 h0, h1;
#pragma unroll
      for (int i = 0; i < 4; ++i) {
        h0[i] = (f16)af[0][i]; h0[4 + i] = (f16)af[1][i];
        h1[i] = (f16)af[2][i]; h1[4 + i] = (f16)af[3][i];
      }
      *(half8*)(smem + (ab0 ^ asw)) = h0;
      *(half8*)(smem + ((ab0 + 16) ^ asw)) = h1;
    }
    __syncthreads();
    if (kt < 3) { // prefetch next A tile during MFMA
#pragma unroll
      for (int i = 0; i < 4; ++i) af[i] = ((const f32x4*)(Ap + (kt + 1) * 64))[i];
    }
#pragma unroll
    for (int ks = 0; ks < 2; ++ks) {
      half8 av[2], bv[8];
#pragma unroll
      for (int m = 0; m < 2; ++m) {
        int R = wrow + m * 16 + ln;
        av[m] = *(const half8*)(smem + ((unsigned)(R * 128 + ks * 64 + kg * 16) ^ (unsigned)((R & 7) << 4)));
      }
#pragma unroll
      for (int n = 0; n < 8; ++n) {
        int J = wcol + n * 16 + ln;
        bv[n] = *(const half8*)(smem + 8192 + ((unsigned)(J * 128 + ks * 64 + kg * 16) ^ (unsigned)((J & 7) << 4)));
      }
#pragma unroll
      for (int m = 0; m < 2; ++m)
#pragma unroll
        for (int n = 0; n < 8; ++n)
          acc[m][n] = __builtin_amdgcn_mfma_f32_16x16x32_f16(av[m], bv[n], acc[m][n], 0, 0, 0);
    }
  }

  // ---- in-register per-head softmax (head = 32 cols = 2 acc-n x 16 lanes) ----
  float sbv[8];
#pragma unroll
  for (int n = 0; n < 8; ++n) sbv[n] = sbias[b * 256 + wcol + n * 16 + ln];

  float vp0[2][4], vp1[2][4];
#pragma unroll
  for (int m = 0; m < 2; ++m)
#pragma unroll
    for (int r = 0; r < 4; ++r) { vp0[m][r] = 0.f; vp1[m][r] = 0.f; }

#pragma unroll
  for (int k = 0; k < 4; ++k) {
#pragma unroll
    for (int m = 0; m < 2; ++m)
#pragma unroll
      for (int r = 0; r < 4; ++r) {
        float a0 = acc[m][2 * k][r] + sbv[2 * k];
        float a1 = acc[m][2 * k + 1][r] + sbv[2 * k + 1];
        float mx = fmaxf(a0, a1);
#pragma unroll
        for (int msk = 1; msk < 16; msk <<= 1) mx = fmaxf(mx, __shfl_xor(mx, msk, 64));
        float e0 = __expf(a0 - mx), e1 = __expf(a1 - mx);
        float sm = e0 + e1;
#pragma unroll
        for (int msk = 1; msk < 16; msk <<= 1) sm += __shfl_xor(sm, msk, 64);
        float inv = 0.125f / sm;
        vp0[m][r] += e0 * inv;
        vp1[m][r] += e1 * inv;
      }
  }
  { // merge 2 head-halves across waves via padded LDS (conflict-free: stride 33)
    float* vpart = (float*)(smem + 40960);
#pragma unroll
    for (int m = 0; m < 2; ++m)
#pragma unroll
      for (int r = 0; r < 4; ++r) {
        int R = wrow + m * 16 + kg * 4 + r;
        vpart[((w & 1) * 64 + R) * 33 + ln] = vp0[m][r];
        vpart[((w & 1) * 64 + R) * 33 + 16 + ln] = vp1[m][r];
      }
  }
  __syncthreads();

  if (t < 64) { // one lane per row: variance partial, top16, candidates
    const float* vpart = (const float*)(smem + 40960);
    float v[32];
#pragma unroll
    for (int j = 0; j < 32; ++j) v[j] = vpart[t * 33 + j] + vpart[(64 + t) * 33 + j];

    float s2 = 0.f;
#pragma unroll
    for (int j = 0; j < 32; ++j) s2 += v[j] * v[j];
    float vr = (s2 - (1.f / 32.f)) * (1.f / 31.f); // unbiased var, mean=1/32 exact
#pragma unroll
    for (int msk = 1; msk < 64; msk <<= 1) vr += __shfl_xor(vr, msk, 64);
    if (t == 0) varpart[b * 256 + blockIdx.x] = vr;

    // bitonic sort descending (static indices -> registers)
#pragma unroll
    for (int k = 2; k <= 32; k <<= 1) {
#pragma unroll
      for (int j = k >> 1; j > 0; j >>= 1) {
#pragma unroll
        for (int i = 0; i < 32; ++i) {
          int l = i ^ j;
          if (l > i) {
            float a = v[i], c = v[l];
            float hi = fmaxf(a, c), lo = fminf(a, c);
            bool up = ((i & k) == 0);
            v[i] = up ? hi : lo;
            v[l] = up ? lo : hi;
          }
        }
      }
    }
    // similarity candidates for k = 8..16
    float m0 = v[0], se = 0.f, te = 0.f;
    float cn[9];
#pragma unroll
    for (int i = 0; i < 16; ++i) {
      float e = __expf(v[i] - m0);
      se += e; te += v[i] * e;
      if (i >= 7) cn[i - 7] = te / se;
    }
    float* cp = cand + ((size_t)b * 16384 + n0 + t) * 9;
#pragma unroll
    for (int i = 0; i < 9; ++i) cp[i] = cn[i];
  }
}

// ---------------- G2: fused MLP (GEMM+LN+ReLU, GEMM+LN+ReLU, dot+sigmoid) ----------------
__global__ void __launch_bounds__(256, 2) k_g2(
    const float* __restrict__ X, const f16* __restrict__ W1h,
    const float* __restrict__ b1, const float* __restrict__ g1, const float* __restrict__ be1,
    const f16* __restrict__ W2h, const float* __restrict__ b2,
    const float* __restrict__ g2, const float* __restrict__ be2,
    const float* __restrict__ w3, const float* __restrict__ b3,
    float* __restrict__ fi) {
  // stage1: A f16[64][64]@0, B f16[256][64]@8192 ; stage2: W2 tile f16[128][64]@0, h1 f16[64][256]@16384
  __shared__ __align__(16) char smem[49152];
  __shared__ float pS[64][2], pQ[64][2];
  const int r0 = blockIdx.x * 64;
  const int t = threadIdx.x;
  const int w = t >> 6;
  const int lane = t & 63;
  const int ln = lane & 15, kg = lane >> 4;
  const int wrow = (w >> 1) * 32, wcol = (w & 1) * 128;

  f32x4 acc[2][8];
#pragma unroll
  for (int m = 0; m < 2; ++m)
#pragma unroll
    for (int n = 0; n < 8; ++n)
#pragma unroll
      for (int i = 0; i < 4; ++i) acc[m][n][i] = 0.f;

  const int ar = t >> 2, aq = t & 3;
  const float* Ap = X + (size_t)(r0 + ar) * 256 + aq * 16;
  const unsigned asw = (unsigned)((ar & 7) << 4);
  const unsigned ab0 = (unsigned)(ar * 128 + aq * 32);
  const int bj = lane >> 3, bc = lane & 7;
  const char* Bg = (const char*)W1h;

  f32x4 af[4];
#pragma unroll
  for (int i = 0; i < 4; ++i) af[i] = ((const f32x4*)Ap)[i];

#pragma unroll
  for (int kt = 0; kt < 4; ++kt) {
    __syncthreads();
#pragma unroll
    for (int i = 0; i < 8; ++i) { // W1 tile: 256 rows x 64 cols f16 via global_load_lds
      int j0 = w * 64 + i * 8;
      int j = j0 + bj;
      GLOAD16(Bg + (size_t)j * 512 + kt * 128 + ((bc ^ (j & 7)) << 4),
              smem + 8192 + j0 * 128);
    }
    {
      half8 h0, h1;
#pragma unroll
      for (int i = 0; i < 4; ++i) {
        h0[i] = (f16)af[0][i]; h0[4 + i] = (f16)af[1][i];
        h1[i] = (f16)af[2][i]; h1[4 + i] = (f16)af[3][i];
      }
      *(half8*)(smem + (ab0 ^ asw)) = h0;
      *(half8*)(smem + ((ab0 + 16) ^ asw)) = h1;
    }
    __syncthreads();
    if (kt < 3) {
#pragma unroll
      for (int i = 0; i < 4; ++i) af[i] = ((const f32x4*)(Ap + (kt + 1) * 64))[i];
    }
#pragma unroll
    for (int ks = 0; ks < 2; ++ks) {
      half8 av[2], bv[8];
#pragma unroll
      for (int m = 0; m < 2; ++m) {
        int R = wrow + m * 16 + ln;
        av[m] = *(const half8*)(smem + ((unsigned)(R * 128 + ks * 64 + kg * 16) ^ (unsigned)((R & 7) << 4)));
      }
#pragma unroll
      for (int n = 0; n < 8; ++n) {
        int J = wcol + n * 16 + ln;
        bv[n] = *(const half8*)(smem + 8192 + ((unsigned)(J * 128 + ks * 64 + kg * 16) ^ (unsigned)((J & 7) << 4)));
      }
#pragma unroll
      for (int m = 0; m < 2; ++m)
#pragma unroll
        for (int n = 0; n < 8; ++n)
          acc[m][n] = __builtin_amdgcn_mfma_f32_16x16x32_f16(av[m], bv[n], acc[m][n], 0, 0, 0);
    }
  }
  __syncthreads();

  // ---- b1 + LayerNorm1 + ReLU -> h1 (f16, swizzled) ----
  float b1v[8], g1v[8], e1v[8];
#pragma unroll
  for (int n = 0; n < 8; ++n) {
    int J = wcol + n * 16 + ln;
    b1v[n] = b1[J]; g1v[n] = g1[J]; e1v[n] = be1[J];
  }
#pragma unroll
  for (int n = 0; n < 8; ++n)
#pragma unroll
    for (int m = 0; m < 2; ++m)
#pragma unroll
      for (int r = 0; r < 4; ++r) acc[m][n][r] += b1v[n];
#pragma unroll
  for (int m = 0; m < 2; ++m)
#pragma unroll
    for (int r = 0; r < 4; ++r) {
      float s = 0.f, q = 0.f;
#pragma unroll
      for (int n = 0; n < 8; ++n) { float x = acc[m][n][r]; s += x; q += x * x; }
#pragma unroll
      for (int msk = 1; msk < 16; msk <<= 1) { s += __shfl_xor(s, msk, 64); q += __shfl_xor(q, msk, 64); }
      if (ln == 0) { int R = wrow + m * 16 + kg * 4 + r; pS[R][w & 1] = s; pQ[R][w & 1] = q; }
    }
  __syncthreads();
#pragma unroll
  for (int m = 0; m < 2; ++m)
#pragma unroll
    for (int r = 0; r < 4; ++r) {
      int R = wrow + m * 16 + kg * 4 + r;
      float mean = (pS[R][0] + pS[R][1]) * (1.f / 256.f);
      float var = (pQ[R][0] + pQ[R][1]) * (1.f / 256.f) - mean * mean;
      float rstd = rsqrtf(var + 1e-5f);
#pragma unroll
      for (int n = 0; n < 8; ++n) {
        int J = wcol + n * 16 + ln;
        float y = (acc[m][n][r] - mean) * rstd * g1v[n] + e1v[n];
        y = fmaxf(y, 0.f);
        *(f16*)(smem + 16384 + ((unsigned)(R * 512 + J * 2) ^ (unsigned)((R & 7) << 4))) = (f16)y;
      }
    }

  // ---- stage 2: h2 = h1 @ W2^T ----
  f32x4 acc2[2][4];
#pragma unroll
  for (int m = 0; m < 2; ++m)
#pragma unroll
    for (int n = 0; n < 4; ++n)
#pragma unroll
      for (int i = 0; i < 4; ++i) acc2[m][n][i] = 0.f;
  const int wcol2 = (w & 1) * 64;
  const char* B2g = (const char*)W2h;
#pragma unroll
  for (int kt = 0; kt < 4; ++kt) {
    __syncthreads();
#pragma unroll
    for (int i = 0; i < 4; ++i) { // W2 tile: 128 rows x 64 cols f16
      int j0 = w * 32 + i * 8;
      int j = j0 + bj;
      GLOAD16(B2g + (size_t)j * 512 + kt * 128 + ((bc ^ (j & 7)) << 4),
              smem + j0 * 128);
    }
    __syncthreads();
#pragma unroll
    for (int ks = 0; ks < 2; ++ks) {
      half8 av[2], bv[4];
#pragma unroll
      for (int m = 0; m < 2; ++m) {
        int R = wrow + m * 16 + ln;
        av[m] = *(const half8*)(smem + 16384 + ((unsigned)(R * 512 + kt * 128 + ks * 64 + kg * 16) ^ (unsigned)((R & 7) << 4)));
      }
#pragma unroll
      for (int n = 0; n < 4; ++n) {
        int J = wcol2 + n * 16 + ln;
        bv[n] = *(const half8*)(smem + ((unsigned)(J * 128 + ks * 64 + kg * 16) ^ (unsigned)((J & 7) << 4)));
      }
#pragma unroll
      for (int m = 0; m < 2; ++m)
#pragma unroll
        for (int n = 0; n < 4; ++n)
          acc2[m][n] = __builtin_amdgcn_mfma_f32_16x16x32_f16(av[m], bv[n], acc2[m][n], 0, 0, 0);
    }
  }
  __syncthreads();

  // ---- b2 + LayerNorm2 + ReLU + w3 dot + sigmoid ----
  float b2v[4], g2v[4], e2v[4], w3v[4];
#pragma unroll
  for (int n = 0; n < 4; ++n) {
    int J = wcol2 + n * 16 + ln;
    b2v[n] = b2[J]; g2v[n] = g2[J]; e2v[n] = be2[J]; w3v[n] = w3[J];
  }
#pragma unroll
  for (int n = 0; n < 4; ++n)
#pragma unroll
    for (int m = 0; m < 2; ++m)
#pragma unroll
      for (int r = 0; r < 4; ++r) acc2[m][n][r] += b2v[n];
#pragma unroll
  for (int m = 0; m < 2; ++m)
#pragma unroll
    for (int r = 0; r < 4; ++r) {
      float s = 0.f, q = 0.f;
#pragma unroll
      for (int n = 0; n < 4; ++n) { float x = acc2[m][n][r]; s += x; q += x * x; }
#pragma unroll
      for (int msk = 1; msk < 16; msk <<= 1) { s += __shfl_xor(s, msk, 64); q += __shfl_xor(q, msk, 64); }
      if (ln == 0) { int R = wrow + m * 16 + kg * 4 + r; pS[R][w & 1] = s; pQ[R][w & 1] = q; }
    }
  __syncthreads();
  float fp[2][4];
#pragma unroll
  for (int m = 0; m < 2; ++m)
#pragma unroll
    for (int r = 0; r < 4; ++r) {
      int R = wrow + m * 16 + kg * 4 + r;
      float mean = (pS[R][0] + pS[R][1]) * (1.f / 128.f);
      float var = (pQ[R][0] + pQ[R][1]) * (1.f / 128.f) - mean * mean;
      float rstd = rsqrtf(var + 1e-5f);
      float a3 = 0.f;
#pragma unroll
      for (int n = 0; n < 4; ++n) {
        float y = (acc2[m][n][r] - mean) * rstd * g2v[n] + e2v[n];
        y = fmaxf(y, 0.f);
        a3 += y * w3v[n];
      }
#pragma unroll
      for (int msk = 1; msk < 16; msk <<= 1) a3 += __shfl_xor(a3, msk, 64);
      fp[m][r] = a3;
    }
  __syncthreads();
  if (ln == 0) {
#pragma unroll
    for (int m = 0; m < 2; ++m)
#pragma unroll
      for (int r = 0; r < 4; ++r) {
        int R = wrow + m * 16 + kg * 4 + r;
        pS[R][w & 1] = fp[m][r];
      }
  }
  __syncthreads();
  if (((w & 1) == 0) && (ln == 0)) {
    float b3v = b3[0];
#pragma unroll
    for (int m = 0; m < 2; ++m)
#pragma unroll
      for (int r = 0; r < 4; ++r) {
        int R = wrow + m * 16 + kg * 4 + r;
        int rg = r0 + R; // rg = n*16 + b
        float z = pS[R][0] + pS[R][1] + b3v;
        fi[(size_t)(rg & 15) * 16384 + (rg >> 4)] = sigm(z);
      }
  }
}

// ---------------- G3: k_top per batch ----------------
__global__ void k_g3(const float* __restrict__ varpart, const float* __restrict__ kw,
                     int* __restrict__ ktop) {
  int t = threadIdx.x;
  int b = t >> 4, i = t & 15;
  float s = 0.f;
#pragma unroll
  for (int k = 0; k < 16; ++k) s += varpart[b * 256 + i + k * 16];
#pragma unroll
  for (int msk = 1; msk < 16; msk <<= 1) s += __shfl_xor(s, msk, 64);
  if (i == 0) {
    float var = s * (1.f / 16384.f);
    float kws = sigm(kw[0]);
    float ratio = kws * (1.f + var * 0.5f);
    ratio = fminf(fmaxf(ratio, 0.25f), 0.6f);
    int kb = (int)floorf(32.f * ratio);
    if (kb < 1) kb = 1;
    int kt = kb < 16 ? kb : 16;
    if (kt < 8) kt = 8;
    ktop[b] = kt;
  }
}

// ---------------- G4: pick sim candidate, min/max reductions ----------------
__global__ void __launch_bounds__(256) k_g4(
    const float* __restrict__ cand, const float* __restrict__ fi,
    const int* __restrict__ ktop, float* __restrict__ sim,
    unsigned* __restrict__ simMM, unsigned* __restrict__ fiMM) {
  __shared__ float red[4][4];
  int b = blockIdx.x >> 6;
  int n = (blockIdx.x & 63) * 256 + threadIdx.x;
  size_t idx = (size_t)b * 16384 + n;
  int k = ktop[b];
  float sv = cand[idx * 9 + (k - 8)];
  sim[idx] = sv;
  float fv = fi[idx];
  float sn = sv, sx = sv, fn = fv, fx = fv;
#pragma unroll
  for (int msk = 1; msk < 64; msk <<= 1) {
    sn = fminf(sn, __shfl_xor(sn, msk, 64));
    sx = fmaxf(sx, __shfl_xor(sx, msk, 64));
    fn = fminf(fn, __shfl_xor(fn, msk, 64));
    fx = fmaxf(fx, __shfl_xor(fx, msk, 64));
  }
  int w = threadIdx.x >> 6;
  if ((threadIdx.x & 63) == 0) { red[0][w] = sn; red[1][w] = sx; red[2][w] = fn; red[3][w] = fx; }
  __syncthreads();
  if (threadIdx.x == 0) {
    float a = red[0][0], c = red[1][0], d = red[2][0], e = red[3][0];
#pragma unroll
    for (int i = 1; i < 4; ++i) {
      a = fminf(a, red[0][i]); c = fmaxf(c, red[1][i]);
      d = fminf(d, red[2][i]); e = fmaxf(e, red[3][i]);
    }
    atomicMin(&simMM[b * 2 + 0], fmap(a));
    atomicMax(&simMM[b * 2 + 1], fmap(c));
    atomicMin(&fiMM[b * 2 + 0], fmap(d));
    atomicMax(&fiMM[b * 2 + 1], fmap(e));
  }
}

// ---------------- G5: normalize, combine, transpose-write ----------------
__global__ void __launch_bounds__(256) k_g5(
    const float* __restrict__ sim, const float* __restrict__ fi,
    const unsigned* __restrict__ simMM, const unsigned* __restrict__ fiMM,
    const float* __restrict__ ac, const float* __restrict__ af,
    float* __restrict__ out) {
  __shared__ float ls[256][17], lf[256][17];
  __shared__ float sMin[16], sInv[16], fMin[16], fInv[16];
  int t = threadIdx.x;
  int n0 = blockIdx.x * 256;
  if (t < 16) {
    float lo = funmap(simMM[t * 2]), hi = funmap(simMM[t * 2 + 1]);
    float r = hi - lo;
    sMin[t] = lo; sInv[t] = (r > 0.f) ? 1.f / r : 0.f;
    lo = funmap(fiMM[t * 2]); hi = funmap(fiMM[t * 2 + 1]);
    r = hi - lo;
    fMin[t] = lo; fInv[t] = (r > 0.f) ? 1.f / r : 0.f;
  }
#pragma unroll
  for (int i = 0; i < 16; ++i) {
    ls[t][i] = sim[(size_t)i * 16384 + n0 + t];
    lf[t][i] = fi[(size_t)i * 16384 + n0 + t];
  }
  __syncthreads();
  float alpha = 0.5f * (sigm(ac[0]) + sigm(af[0]));
  float o[16];
#pragma unroll
  for (int b = 0; b < 16; ++b) {
    float s = (ls[t][b] - sMin[b]) * sInv[b];
    float f = (lf[t][b] - fMin[b]) * fInv[b];
    o[b] = alpha * s + (1.f - alpha) * f;
  }
  float* op = out + (size_t)(n0 + t) * 16;
#pragma unroll
  for (int i = 0; i < 4; ++i) {
    f32x4 v;
    v[0] = o[i * 4]; v[1] = o[i * 4 + 1]; v[2] = o[i * 4 + 2]; v[3] = o[i * 4 + 3];
    *(f32x4*)(op + i * 4) = v;
  }
}

// ---------------- launcher ----------------
extern "C" void kernel_launch(void* const* d_in, const int* in_sizes, int n_in,
                              void* d_out, int out_size, void* d_ws, size_t ws_size,
                              hipStream_t stream) {
  const float* X    = (const float*)d_in[0];
  const float* T    = (const float*)d_in[1];
  const float* vp_w = (const float*)d_in[2];
  const float* vp_b = (const float*)d_in[3];
  const float* tp_w = (const float*)d_in[4];
  const float* tp_b = (const float*)d_in[5];
  const float* ipw  = (const float*)d_in[6];
  const float* ipb  = (const float*)d_in[7];
  const float* w1   = (const float*)d_in[8];
  const float* b1   = (const float*)d_in[9];
  const float* g1   = (const float*)d_in[10];
  const float* be1  = (const float*)d_in[11];
  const float* w2   = (const float*)d_in[12];
  const float* b2   = (const float*)d_in[13];
  const float* g2   = (const float*)d_in[14];
  const float* be2  = (const float*)d_in[15];
  const float* w3   = (const float*)d_in[16];
  const float* b3   = (const float*)d_in[17];
  const float* kw   = (const float*)d_in[18];
  const float* ac   = (const float*)d_in[19];
  const float* af   = (const float*)d_in[20];
  char* ws = (char*)d_ws;
  float* Wqv = (float*)(ws + WQV_OFF);
  float* Wkt = (float*)(ws + WKT_OFF);
  float* kp = (float*)(ws + KP_OFF);
  f16* W2s = (f16*)(ws + W2S_OFF);
  float* sbias = (float*)(ws + SBIAS_OFF);
  float* bqv = (float*)(ws + BQV_OFF);
  float* bkt = (float*)(ws + BKT_OFF);
  f16* W1h = (f16*)(ws + W1H_OFF);
  f16* W2h = (f16*)(ws + W2H_OFF);
  float* varpart = (float*)(ws + VARP_OFF);
  int* ktop = (int*)(ws + KTOP_OFF);
  unsigned* simMM = (unsigned*)(ws + SMM_OFF);
  unsigned* fiMM = (unsigned*)(ws + FMM_OFF);
  float* cand = (float*)(ws + CAND_OFF);
  float* fi = (float*)(ws + FI_OFF);
  float* sim = (float*)(ws + SIM_OFF);
  float* out = (float*)d_out;

  k_init<<<1, 32, 0, stream>>>(simMM, fiMM);
  k_p1<<<dim3(16, 16, 3), dim3(16, 16), 0, stream>>>(ipw, ipb, vp_w, vp_b, tp_w, tp_b, Wqv, Wkt, bqv, bkt);
  k_conv<<<384, 256, 0, stream>>>(w1, w2, W1h, W2h);
  k_p2<<<dim3(16, 32), dim3(16, 16), 0, stream>>>(T, Wkt, bkt, kp);
  k_p3<<<dim3(16, 16, 16), dim3(16, 16), 0, stream>>>(kp, Wqv, bqv, W2s, sbias);
  k_g1<<<dim3(256, 16), 256, 0, stream>>>(X, W2s, sbias, cand, varpart);
  k_g2<<<4096, 256, 0, stream>>>(X, W1h, b1, g1, be1, W2h, b2, g2, be2, w3, b3, fi);
  k_g3<<<1, 256, 0, stream>>>(varpart, kw, ktop);
  k_g4<<<1024, 256, 0, stream>>>(cand, fi, ktop, sim, simMM, fiMM);
  k_g5<<<64, 256, 0, stream>>>(sim, fi, simMM, fiMM, ac, af, out);
}